// Round 1
// baseline (1039.052 us; speedup 1.0000x reference)
//
#include <hip/hip_runtime.h>
#include <hip/hip_bf16.h>

// ---------------------------------------------------------------------------
// NeRF fused MLP, bf16 MFMA (16x16x32), fp32 accum.
// Block = 256 threads (4 waves), 128 rows/block, activations in LDS (swizzled),
// weights repacked to bf16 [col][Kpad] in d_ws by a prep kernel.
// ---------------------------------------------------------------------------

typedef __bf16 bfrag __attribute__((ext_vector_type(8)));   // 8 bf16 = 4 VGPR
typedef float  f4    __attribute__((ext_vector_type(4)));   // C/D frag

#define LDSK 256   // LDS activation row stride (bf16 elems)

// ws layout (bf16 element offsets)
constexpr int OFF_W0 = 0;        // 256 x 64
constexpr int OFF_W1 = 16384;    // 256 x 256
constexpr int OFF_W2 = 81920;
constexpr int OFF_W3 = 147456;
constexpr int OFF_W4 = 212992;
constexpr int OFF_W5 = 278528;   // 256 x 320 (skip layer, shifted: k63 = 0)
constexpr int OFF_W6 = 360448;
constexpr int OFF_W7 = 425984;
constexpr int OFF_WF = 491520;   // 256 x 256
constexpr int OFF_WV = 557056;   // 128 x 320
constexpr int WS_TOTAL = 598016; // bf16 elems (~1.2 MB)

__device__ __forceinline__ unsigned swz_idx(int row, int k) {
  // row-major [128][256] bf16 with 16B-chunk XOR swizzle (T2-style):
  // flips ushort-index bits 3..5 by row&7 -> stride-512B column reads are 2-way (free)
  return (unsigned)((row * LDSK + k) ^ ((row & 7) << 3));
}

__device__ __forceinline__ float bf2f(unsigned short u) {
  return __builtin_bit_cast(float, (unsigned)((unsigned)u << 16));
}

template<int RT, int CT>
__device__ __forceinline__ void zero_acc(f4 (&acc)[RT][CT]) {
#pragma unroll
  for (int rt = 0; rt < RT; ++rt)
#pragma unroll
    for (int ct = 0; ct < CT; ++ct)
      acc[rt][ct] = (f4){0.f, 0.f, 0.f, 0.f};
}

// K-phase sourced from LDS activations. kg0 = weight k offset of first kstep,
// lds_koff subtracted to get LDS k index.
template<int RT, int CT, int NKS>
__device__ __forceinline__ void phase_lds(f4 (&acc)[RT][CT],
    const unsigned short* __restrict__ hin,
    const unsigned short* __restrict__ wt, int kpad,
    int kg0, int lds_koff, int r0w, int c0w, int l15, int lk8) {
#pragma unroll
  for (int ks = 0; ks < NKS; ++ks) {
    const int kg = kg0 + ks * 32 + lk8;
    bfrag a[RT], b[CT];
#pragma unroll
    for (int rt = 0; rt < RT; ++rt) {
      const int row = r0w + rt * 16 + l15;
      a[rt] = *(const bfrag*)(hin + swz_idx(row, kg - lds_koff));
    }
#pragma unroll
    for (int ct = 0; ct < CT; ++ct) {
      const int col = c0w + ct * 16 + l15;
      b[ct] = *(const bfrag*)(wt + (size_t)col * kpad + kg);
    }
#pragma unroll
    for (int rt = 0; rt < RT; ++rt)
#pragma unroll
      for (int ct = 0; ct < CT; ++ct)
        acc[rt][ct] = __builtin_amdgcn_mfma_f32_16x16x32_bf16(a[rt], b[ct], acc[rt][ct], 0, 0, 0);
  }
}

// K-phase sourced from global x (fp32 -> bf16 on the fly).
// VIEWS=false: pts = x[:, 0:63]  (k local 0..62 valid, 63 -> 0)
// VIEWS=true : views = x[:, 63:126] (same mask)
// kg0 = weight k offset of local k 0.
template<int RT, int CT, int NKS, bool VIEWS>
__device__ __forceinline__ void phase_x(f4 (&acc)[RT][CT],
    const float* __restrict__ x,
    const unsigned short* __restrict__ wt, int kpad,
    int kg0, int r0g, int c0w, int l15, int lk8) {
#pragma unroll
  for (int ks = 0; ks < NKS; ++ks) {
    const int klocal = ks * 32 + lk8;   // 0..63 across lanes
    bfrag a[RT], b[CT];
#pragma unroll
    for (int rt = 0; rt < RT; ++rt) {
      const int row = r0g + rt * 16 + l15;
      const float* xp = x + (size_t)row * 126 + (VIEWS ? 63 : 0) + klocal;
      bfrag av;
#pragma unroll
      for (int j = 0; j < 8; ++j) {
        float f = (klocal + j < 63) ? xp[j] : 0.f;
        av[j] = (__bf16)f;
      }
      a[rt] = av;
    }
#pragma unroll
    for (int ct = 0; ct < CT; ++ct) {
      const int col = c0w + ct * 16 + l15;
      b[ct] = *(const bfrag*)(wt + (size_t)col * kpad + kg0 + klocal);
    }
#pragma unroll
    for (int rt = 0; rt < RT; ++rt)
#pragma unroll
      for (int ct = 0; ct < CT; ++ct)
        acc[rt][ct] = __builtin_amdgcn_mfma_f32_16x16x32_bf16(a[rt], b[ct], acc[rt][ct], 0, 0, 0);
  }
}

// bias + (relu) + bf16 store to LDS. C/D layout: col = lane&15, row = (lane>>4)*4 + j
template<int RT, int CT, bool RELU>
__device__ __forceinline__ void epilogue(f4 (&acc)[RT][CT],
    unsigned short* __restrict__ hout, const float* __restrict__ bias,
    int r0w, int c0w, int l15, int lk4) {
#pragma unroll
  for (int ct = 0; ct < CT; ++ct) {
    const int col = c0w + ct * 16 + l15;
    const float bv = bias[col];
#pragma unroll
    for (int rt = 0; rt < RT; ++rt) {
#pragma unroll
      for (int j = 0; j < 4; ++j) {
        const int row = r0w + rt * 16 + lk4 + j;
        float v = acc[rt][ct][j] + bv;
        if (RELU) v = fmaxf(v, 0.f);
        __bf16 bb = (__bf16)v;
        hout[swz_idx(row, col)] = __builtin_bit_cast(unsigned short, bb);
      }
    }
  }
}

// ---------------------------------------------------------------------------
struct RepackArgs {
  const float *W0, *W1, *W2, *W3, *W4, *W5, *W6, *W7, *Wf, *Wv;
  unsigned short* ws;
};

__global__ void repack_kernel(RepackArgs a) {
  const int i = blockIdx.x * 256 + threadIdx.x;
  if (i >= WS_TOTAL) return;
  const float* src; int off, kpad, fanout, fanin; bool shift = false;
  if      (i < OFF_W1) { src = a.W0; off = OFF_W0; kpad = 64;  fanout = 256; fanin = 63; }
  else if (i < OFF_W2) { src = a.W1; off = OFF_W1; kpad = 256; fanout = 256; fanin = 256; }
  else if (i < OFF_W3) { src = a.W2; off = OFF_W2; kpad = 256; fanout = 256; fanin = 256; }
  else if (i < OFF_W4) { src = a.W3; off = OFF_W3; kpad = 256; fanout = 256; fanin = 256; }
  else if (i < OFF_W5) { src = a.W4; off = OFF_W4; kpad = 256; fanout = 256; fanin = 256; }
  else if (i < OFF_W6) { src = a.W5; off = OFF_W5; kpad = 320; fanout = 256; fanin = 319; shift = true; }
  else if (i < OFF_W7) { src = a.W6; off = OFF_W6; kpad = 256; fanout = 256; fanin = 256; }
  else if (i < OFF_WF) { src = a.W7; off = OFF_W7; kpad = 256; fanout = 256; fanin = 256; }
  else if (i < OFF_WV) { src = a.Wf; off = OFF_WF; kpad = 256; fanout = 256; fanin = 256; }
  else                 { src = a.Wv; off = OFF_WV; kpad = 320; fanout = 128; fanin = 319; }
  const int idx = i - off;
  const int c  = idx / kpad;
  const int kp = idx % kpad;
  float v;
  if (shift) { // W5: k 0..62 = pts rows, k63 = 0 (alignment pad), k64..319 = h rows 63..318
    v = (kp < 63) ? src[(size_t)kp * 256 + c]
                  : ((kp == 63) ? 0.f : src[(size_t)(kp - 1) * 256 + c]);
  } else {
    v = (kp < fanin) ? src[(size_t)kp * fanout + c] : 0.f;
  }
  __bf16 bb = (__bf16)v;
  a.ws[i] = __builtin_bit_cast(unsigned short, bb);
}

// ---------------------------------------------------------------------------
struct MainArgs {
  const float* x;
  const unsigned short* ws;
  const float *b0, *b1, *b2, *b3, *b4, *b5, *b6, *b7;
  const float *bfc, *Wa, *ba, *bv, *Wr, *br;
  float* out;
};

__global__ __launch_bounds__(256, 1) void nerf_kernel(MainArgs A) {
  extern __shared__ unsigned short lds[];
  unsigned short* hA = lds;                 // [128][256] bf16, swizzled
  unsigned short* hB = lds + 128 * 256;

  const int tid  = threadIdx.x;
  const int lane = tid & 63;
  const int wave = tid >> 6;
  const int wm = wave >> 1, wn = wave & 1;  // 2x2 wave grid
  const int l15 = lane & 15;
  const int lk8 = (lane >> 4) << 3;
  const int lk4 = (lane >> 4) << 2;
  const int r0w = wm * 64;                  // local row base (64 rows per wave)
  const int c0w = wn * 128;                 // col base (128 cols per wave)
  const int blockRow = blockIdx.x * 128;

  const unsigned short* ws = A.ws;
  f4 acc[4][8];

  // L0: pts(x) -> hA   (K = 64)
  zero_acc(acc);
  phase_x<4, 8, 2, false>(acc, A.x, ws + OFF_W0, 64, 0, blockRow + r0w, c0w, l15, lk8);
  epilogue<4, 8, true>(acc, hA, A.b0, r0w, c0w, l15, lk4);
  __syncthreads();

  // L1: hA -> hB
  zero_acc(acc);
  phase_lds<4, 8, 8>(acc, hA, ws + OFF_W1, 256, 0, 0, r0w, c0w, l15, lk8);
  epilogue<4, 8, true>(acc, hB, A.b1, r0w, c0w, l15, lk4);
  __syncthreads();

  // L2: hB -> hA
  zero_acc(acc);
  phase_lds<4, 8, 8>(acc, hB, ws + OFF_W2, 256, 0, 0, r0w, c0w, l15, lk8);
  epilogue<4, 8, true>(acc, hA, A.b2, r0w, c0w, l15, lk4);
  __syncthreads();

  // L3: hA -> hB
  zero_acc(acc);
  phase_lds<4, 8, 8>(acc, hA, ws + OFF_W3, 256, 0, 0, r0w, c0w, l15, lk8);
  epilogue<4, 8, true>(acc, hB, A.b3, r0w, c0w, l15, lk4);
  __syncthreads();

  // L4: hB -> hA
  zero_acc(acc);
  phase_lds<4, 8, 8>(acc, hB, ws + OFF_W4, 256, 0, 0, r0w, c0w, l15, lk8);
  epilogue<4, 8, true>(acc, hA, A.b4, r0w, c0w, l15, lk4);
  __syncthreads();

  // L5 (skip): [pts | hA] @ W5 -> hB  (K = 64 + 256, weight k: 0..63 pts, 64..319 h)
  zero_acc(acc);
  phase_x<4, 8, 2, false>(acc, A.x, ws + OFF_W5, 320, 0, blockRow + r0w, c0w, l15, lk8);
  phase_lds<4, 8, 8>(acc, hA, ws + OFF_W5, 320, 64, 64, r0w, c0w, l15, lk8);
  epilogue<4, 8, true>(acc, hB, A.b5, r0w, c0w, l15, lk4);
  __syncthreads();

  // L6: hB -> hA
  zero_acc(acc);
  phase_lds<4, 8, 8>(acc, hB, ws + OFF_W6, 256, 0, 0, r0w, c0w, l15, lk8);
  epilogue<4, 8, true>(acc, hA, A.b6, r0w, c0w, l15, lk4);
  __syncthreads();

  // L7: hA -> hB   (h_final in hB)
  zero_acc(acc);
  phase_lds<4, 8, 8>(acc, hA, ws + OFF_W7, 256, 0, 0, r0w, c0w, l15, lk8);
  epilogue<4, 8, true>(acc, hB, A.b7, r0w, c0w, l15, lk4);
  __syncthreads();

  // alpha = h_final @ Wa + ba   (VALU; 2 threads per row)
  {
    const int row = tid >> 1, half = tid & 1;
    float s = 0.f;
    const float* wa = A.Wa;
    for (int kk = half * 128; kk < half * 128 + 128; kk += 8) {
      const unsigned short* p = hB + swz_idx(row, kk);
#pragma unroll
      for (int j = 0; j < 8; ++j) s += bf2f(p[j]) * wa[kk + j];
    }
    s += __shfl_xor(s, 1);
    if (half == 0) A.out[(size_t)(blockRow + row) * 4 + 3] = s + A.ba[0];
  }

  // feature = h_final @ Wf + bf (NO relu): hB -> hA
  zero_acc(acc);
  phase_lds<4, 8, 8>(acc, hB, ws + OFF_WF, 256, 0, 0, r0w, c0w, l15, lk8);
  epilogue<4, 8, false>(acc, hA, A.bfc, r0w, c0w, l15, lk4);
  __syncthreads();

  // hv = relu([feature | views] @ Wv + bv): hA + x -> hB[:, 0:128]
  {
    f4 acc2[4][4];
    zero_acc(acc2);
    const int c0v = wn * 64;   // 64 cols per wave (128 total)
    phase_lds<4, 4, 8>(acc2, hA, ws + OFF_WV, 320, 0, 0, r0w, c0v, l15, lk8);
    phase_x<4, 4, 2, true>(acc2, A.x, ws + OFF_WV, 320, 256, blockRow + r0w, c0v, l15, lk8);
    epilogue<4, 4, true>(acc2, hB, A.bv, r0w, c0v, l15, lk4);
  }
  __syncthreads();

  // rgb = hv @ Wr + br  (VALU; 2 threads per row)
  {
    const int row = tid >> 1, half = tid & 1;
    float s0 = 0.f, s1 = 0.f, s2 = 0.f;
    for (int kk = half * 64; kk < half * 64 + 64; kk += 8) {
      const unsigned short* p = hB + swz_idx(row, kk);
#pragma unroll
      for (int j = 0; j < 8; ++j) {
        const float h = bf2f(p[j]);
        const float* wr = A.Wr + (size_t)(kk + j) * 3;
        s0 += h * wr[0]; s1 += h * wr[1]; s2 += h * wr[2];
      }
    }
    s0 += __shfl_xor(s0, 1); s1 += __shfl_xor(s1, 1); s2 += __shfl_xor(s2, 1);
    if (half == 0) {
      float* o = A.out + (size_t)(blockRow + row) * 4;
      o[0] = s0 + A.br[0]; o[1] = s1 + A.br[1]; o[2] = s2 + A.br[2];
    }
  }
}

// ---------------------------------------------------------------------------
extern "C" void kernel_launch(void* const* d_in, const int* in_sizes, int n_in,
                              void* d_out, int out_size, void* d_ws, size_t ws_size,
                              hipStream_t stream) {
  // d_in order: x, W0,b0, W1,b1, ..., W7,b7, Wf,bf, Wa,ba, Wv,bv, Wr,br
  RepackArgs ra;
  ra.W0 = (const float*)d_in[1];  ra.W1 = (const float*)d_in[3];
  ra.W2 = (const float*)d_in[5];  ra.W3 = (const float*)d_in[7];
  ra.W4 = (const float*)d_in[9];  ra.W5 = (const float*)d_in[11];
  ra.W6 = (const float*)d_in[13]; ra.W7 = (const float*)d_in[15];
  ra.Wf = (const float*)d_in[17]; ra.Wv = (const float*)d_in[21];
  ra.ws = (unsigned short*)d_ws;
  repack_kernel<<<(WS_TOTAL + 255) / 256, 256, 0, stream>>>(ra);

  MainArgs ma;
  ma.x   = (const float*)d_in[0];
  ma.ws  = (const unsigned short*)d_ws;
  ma.b0  = (const float*)d_in[2];  ma.b1 = (const float*)d_in[4];
  ma.b2  = (const float*)d_in[6];  ma.b3 = (const float*)d_in[8];
  ma.b4  = (const float*)d_in[10]; ma.b5 = (const float*)d_in[12];
  ma.b6  = (const float*)d_in[14]; ma.b7 = (const float*)d_in[16];
  ma.bfc = (const float*)d_in[18];
  ma.Wa  = (const float*)d_in[19]; ma.ba = (const float*)d_in[20];
  ma.bv  = (const float*)d_in[22];
  ma.Wr  = (const float*)d_in[23]; ma.br = (const float*)d_in[24];
  ma.out = (float*)d_out;

  const int n    = in_sizes[0] / 126;   // 131072
  const int grid = n / 128;             // 1024 blocks

  hipFuncSetAttribute(reinterpret_cast<const void*>(nerf_kernel),
                      hipFuncAttributeMaxDynamicSharedMemorySize, 131072);
  nerf_kernel<<<grid, 256, 131072, stream>>>(ma);
}

// Round 2
// 945.716 us; speedup vs baseline: 1.0987x; 1.0987x over previous
//
#include <hip/hip_runtime.h>
#include <hip/hip_bf16.h>

// ---------------------------------------------------------------------------
// NeRF fused MLP, bf16 MFMA (16x16x32), fp32 accum.
// 4 waves/block, each wave owns an independent 32-row x 256-col tile:
// NO __syncthreads anywhere. Per-wave LDS: h[32][256] (in-place across layers,
// swizzled) + pts/views[32][64]. 80 KiB/block -> 2 blocks/CU.
// Weights repacked to bf16 [col][Kpad] in d_ws (incl. padded Wa/Wr tails).
// ---------------------------------------------------------------------------

typedef __bf16 bfrag __attribute__((ext_vector_type(8)));   // 8 bf16 = 4 VGPR
typedef float  f4    __attribute__((ext_vector_type(4)));   // C/D frag

// ws layout (bf16 element offsets)
constexpr int OFF_W0 = 0;        // 256 x 64
constexpr int OFF_W1 = 16384;    // 256 x 256
constexpr int OFF_W2 = 81920;
constexpr int OFF_W3 = 147456;
constexpr int OFF_W4 = 212992;
constexpr int OFF_W5 = 278528;   // 256 x 320 (skip layer, shifted: k63 = 0)
constexpr int OFF_W6 = 360448;
constexpr int OFF_W7 = 425984;
constexpr int OFF_WF = 491520;   // 256 x 256
constexpr int OFF_WV = 557056;   // 128 x 320
constexpr int OFF_WA = 598016;   // 16 x 256 (col 0 = Wa, rest 0)
constexpr int OFF_WR = 602112;   // 16 x 128 (cols 0..2 = Wr, rest 0)
constexpr int WS_TOTAL = 604160; // bf16 elems (~1.2 MB)

__device__ __forceinline__ unsigned swz(int row, int k, int stride) {
  // XOR-swizzle bits 3..5 of the k-index by row&7: 16B chunks stay contiguous,
  // stride-512B (or 128B) column reads become <=2-way (free).
  return (unsigned)((row * stride + k) ^ ((row & 7) << 3));
}

// ---------------------------------------------------------------------------
// stage x[:, COL0 : COL0+63] (fp32) -> bf16 LDS tile [32][64] (k63 -> 0 pad)
template<int COL0>
__device__ __forceinline__ void stage_x(const float* __restrict__ x,
    unsigned short* dst, int rowg0, int l15, int lk8) {
#pragma unroll
  for (int ks = 0; ks < 2; ++ks) {
    const int kl = ks * 32 + lk8;
#pragma unroll
    for (int rt = 0; rt < 2; ++rt) {
      const int rowg = rowg0 + rt * 16 + l15;
      const float* xp = x + (size_t)rowg * 126 + COL0 + kl;
      float f[8];
      if (COL0 == 0) {
        // row*126 + kl is even -> 8B aligned; reading k=63 is in-bounds (views[0])
#pragma unroll
        for (int p = 0; p < 4; ++p) {
          float2 t = *(const float2*)(xp + 2 * p);
          f[2 * p] = t.x; f[2 * p + 1] = t.y;
        }
      } else {
        // views start at odd offset; guard the load itself (k=63 could be OOB)
#pragma unroll
        for (int j = 0; j < 8; ++j) f[j] = (kl + j < 63) ? xp[j] : 0.f;
      }
      bfrag av;
#pragma unroll
      for (int j = 0; j < 8; ++j)
        av[j] = (kl + j < 63) ? (__bf16)f[j] : (__bf16)0.f;
      *(bfrag*)(dst + swz(rt * 16 + l15, kl, 64)) = av;
    }
  }
}

// MFMA phase over 8 col-tiles (128 output cols at c0), K = NKS*32 from LDS.
template<int NKS>
__device__ __forceinline__ void phase8(f4 (&acc)[2][8],
    const unsigned short* hin, int hstride,
    const unsigned short* wt, int kpad, int kg0, int c0,
    int l15, int lk8) {
#pragma unroll
  for (int ks = 0; ks < NKS; ++ks) {
    const int kl = ks * 32 + lk8;
    bfrag b[8];
#pragma unroll
    for (int ct = 0; ct < 8; ++ct) {
      const int col = c0 + ct * 16 + l15;
      b[ct] = *(const bfrag*)(wt + (size_t)col * kpad + kg0 + kl);
    }
    bfrag a[2];
#pragma unroll
    for (int rt = 0; rt < 2; ++rt)
      a[rt] = *(const bfrag*)(hin + swz(rt * 16 + l15, kl, hstride));
#pragma unroll
    for (int rt = 0; rt < 2; ++rt)
#pragma unroll
      for (int ct = 0; ct < 8; ++ct)
        acc[rt][ct] = __builtin_amdgcn_mfma_f32_16x16x32_bf16(a[rt], b[ct], acc[rt][ct], 0, 0, 0);
  }
}

// MFMA phase with a single 16-col tile (padded tail weights Wa/Wr).
template<int NKS>
__device__ __forceinline__ void phase1(f4 (&acc)[2],
    const unsigned short* hin, int hstride,
    const unsigned short* wt, int kpad,
    int l15, int lk8) {
#pragma unroll
  for (int ks = 0; ks < NKS; ++ks) {
    const int kl = ks * 32 + lk8;
    bfrag b = *(const bfrag*)(wt + (size_t)l15 * kpad + kl);
    bfrag a[2];
#pragma unroll
    for (int rt = 0; rt < 2; ++rt)
      a[rt] = *(const bfrag*)(hin + swz(rt * 16 + l15, kl, hstride));
#pragma unroll
    for (int rt = 0; rt < 2; ++rt)
      acc[rt] = __builtin_amdgcn_mfma_f32_16x16x32_bf16(a[rt], b, acc[rt], 0, 0, 0);
  }
}

__device__ __forceinline__ void init8(f4 (&acc)[2][8], const float* bias,
                                      int c0, int l15) {
#pragma unroll
  for (int ct = 0; ct < 8; ++ct) {
    const float bv = bias[c0 + ct * 16 + l15];
    f4 v = {bv, bv, bv, bv};
    acc[0][ct] = v; acc[1][ct] = v;
  }
}

template<bool RELU>
__device__ __forceinline__ void store8(f4 (&acc)[2][8], unsigned short* hout,
    int hstride, int c0, int l15, int lk4) {
#pragma unroll
  for (int ct = 0; ct < 8; ++ct) {
    const int col = c0 + ct * 16 + l15;
#pragma unroll
    for (int rt = 0; rt < 2; ++rt)
#pragma unroll
      for (int j = 0; j < 4; ++j) {
        float v = acc[rt][ct][j];
        if (RELU) v = fmaxf(v, 0.f);
        __bf16 bb = (__bf16)v;
        hout[swz(rt * 16 + lk4 + j, col, hstride)] = __builtin_bit_cast(unsigned short, bb);
      }
  }
}

// standard 256->256 layer, in-place in h (reads all precede writes, same wave)
template<bool RELU>
__device__ __forceinline__ void layer256(f4 (&acc)[2][2][8],
    unsigned short* h, const unsigned short* wt, const float* bias,
    int l15, int lk8, int lk4) {
#pragma unroll
  for (int ch = 0; ch < 2; ++ch) {
    init8(acc[ch], bias, ch * 128, l15);
    phase8<8>(acc[ch], h, 256, wt, 256, 0, ch * 128, l15, lk8);
  }
#pragma unroll
  for (int ch = 0; ch < 2; ++ch)
    store8<RELU>(acc[ch], h, 256, ch * 128, l15, lk4);
}

// ---------------------------------------------------------------------------
struct RepackArgs {
  const float *W0, *W1, *W2, *W3, *W4, *W5, *W6, *W7, *Wf, *Wv, *Wa, *Wr;
  unsigned short* ws;
};

__global__ void repack_kernel(RepackArgs a) {
  const int i = blockIdx.x * 256 + threadIdx.x;
  if (i >= WS_TOTAL) return;
  float v;
  if (i >= OFF_WR) {               // WR: 16 x 128, cols 0..2 from Wr [128][3]
    const int idx = i - OFF_WR;
    const int c = idx / 128, kp = idx % 128;
    v = (c < 3) ? a.Wr[(size_t)kp * 3 + c] : 0.f;
  } else if (i >= OFF_WA) {        // WA: 16 x 256, col 0 from Wa [256][1]
    const int idx = i - OFF_WA;
    const int c = idx / 256, kp = idx % 256;
    v = (c == 0) ? a.Wa[kp] : 0.f;
  } else {
    const float* src; int off, kpad, fanout, fanin; bool shift = false;
    if      (i < OFF_W1) { src = a.W0; off = OFF_W0; kpad = 64;  fanout = 256; fanin = 63; }
    else if (i < OFF_W2) { src = a.W1; off = OFF_W1; kpad = 256; fanout = 256; fanin = 256; }
    else if (i < OFF_W3) { src = a.W2; off = OFF_W2; kpad = 256; fanout = 256; fanin = 256; }
    else if (i < OFF_W4) { src = a.W3; off = OFF_W3; kpad = 256; fanout = 256; fanin = 256; }
    else if (i < OFF_W5) { src = a.W4; off = OFF_W4; kpad = 256; fanout = 256; fanin = 256; }
    else if (i < OFF_W6) { src = a.W5; off = OFF_W5; kpad = 320; fanout = 256; fanin = 319; shift = true; }
    else if (i < OFF_W7) { src = a.W6; off = OFF_W6; kpad = 256; fanout = 256; fanin = 256; }
    else if (i < OFF_WF) { src = a.W7; off = OFF_W7; kpad = 256; fanout = 256; fanin = 256; }
    else if (i < OFF_WV) { src = a.Wf; off = OFF_WF; kpad = 256; fanout = 256; fanin = 256; }
    else                 { src = a.Wv; off = OFF_WV; kpad = 320; fanout = 128; fanin = 319; }
    const int idx = i - off;
    const int c  = idx / kpad;
    const int kp = idx % kpad;
    if (shift) { // W5: k 0..62 = pts rows, k63 = 0 pad, k64..319 = h rows 63..318
      v = (kp < 63) ? src[(size_t)kp * 256 + c]
                    : ((kp == 63) ? 0.f : src[(size_t)(kp - 1) * 256 + c]);
    } else {
      v = (kp < fanin) ? src[(size_t)kp * fanout + c] : 0.f;
    }
  }
  __bf16 bb = (__bf16)v;
  a.ws[i] = __builtin_bit_cast(unsigned short, bb);
}

// ---------------------------------------------------------------------------
struct MainArgs {
  const float* x;
  const unsigned short* ws;
  const float *b0, *b1, *b2, *b3, *b4, *b5, *b6, *b7;
  const float *bfc, *ba, *bv, *br;
  float* out;
};

__global__ __launch_bounds__(256, 2) void nerf_kernel(MainArgs A) {
  extern __shared__ unsigned short lds[];
  const int tid  = threadIdx.x;
  const int lane = tid & 63;
  const int wave = tid >> 6;
  const int l15 = lane & 15;
  const int lk8 = (lane >> 4) << 3;
  const int lk4 = (lane >> 4) << 2;
  unsigned short* h   = lds + wave * (32 * 256 + 32 * 64);  // [32][256] swizzled
  unsigned short* pts = h + 32 * 256;                       // [32][64]  swizzled
  const int rowg0 = blockIdx.x * 128 + wave * 32;
  const unsigned short* ws = A.ws;
  f4 acc[2][2][8];

  // stage pts (x[:,0:63]) -> LDS, then L0 (K=64): pts -> h
  stage_x<0>(A.x, pts, rowg0, l15, lk8);
#pragma unroll
  for (int ch = 0; ch < 2; ++ch) {
    init8(acc[ch], A.b0, ch * 128, l15);
    phase8<2>(acc[ch], pts, 64, ws + OFF_W0, 64, 0, ch * 128, l15, lk8);
  }
#pragma unroll
  for (int ch = 0; ch < 2; ++ch)
    store8<true>(acc[ch], h, 256, ch * 128, l15, lk4);

  layer256<true>(acc, h, ws + OFF_W1, A.b1, l15, lk8, lk4);
  layer256<true>(acc, h, ws + OFF_W2, A.b2, l15, lk8, lk4);
  layer256<true>(acc, h, ws + OFF_W3, A.b3, l15, lk8, lk4);
  layer256<true>(acc, h, ws + OFF_W4, A.b4, l15, lk8, lk4);

  // L5 (skip): [pts | h] @ W5 -> h   (weight k: 0..63 pts(pad63), 64..319 h)
#pragma unroll
  for (int ch = 0; ch < 2; ++ch) {
    init8(acc[ch], A.b5, ch * 128, l15);
    phase8<2>(acc[ch], pts, 64, ws + OFF_W5, 320, 0,  ch * 128, l15, lk8);
    phase8<8>(acc[ch], h, 256, ws + OFF_W5, 320, 64, ch * 128, l15, lk8);
  }
#pragma unroll
  for (int ch = 0; ch < 2; ++ch)
    store8<true>(acc[ch], h, 256, ch * 128, l15, lk4);

  layer256<true>(acc, h, ws + OFF_W6, A.b6, l15, lk8, lk4);
  layer256<true>(acc, h, ws + OFF_W7, A.b7, l15, lk8, lk4);

  // alpha = h_final @ Wa + ba  (padded-weight MFMA, only col l15==0 real)
  {
    f4 acca[2];
    acca[0] = (f4){0.f, 0.f, 0.f, 0.f};
    acca[1] = (f4){0.f, 0.f, 0.f, 0.f};
    phase1<8>(acca, h, 256, ws + OFF_WA, 256, l15, lk8);
    if (l15 == 0) {
      const float ba0 = A.ba[0];
#pragma unroll
      for (int rt = 0; rt < 2; ++rt)
#pragma unroll
        for (int j = 0; j < 4; ++j)
          A.out[(size_t)(rowg0 + rt * 16 + lk4 + j) * 4 + 3] = acca[rt][j] + ba0;
    }
  }

  // feature = h_final @ Wf + bf (NO relu), in-place
  layer256<false>(acc, h, ws + OFF_WF, A.bfc, l15, lk8, lk4);

  // stage views (x[:,63:126]) -> pts buffer (pts dead after L5)
  stage_x<63>(A.x, pts, rowg0, l15, lk8);

  // hv = relu([feature | views] @ Wv + bv) -> h cols 0..127
  init8(acc[0], A.bv, 0, l15);
  phase8<8>(acc[0], h, 256, ws + OFF_WV, 320, 0,   0, l15, lk8);
  phase8<2>(acc[0], pts, 64, ws + OFF_WV, 320, 256, 0, l15, lk8);
  store8<true>(acc[0], h, 256, 0, l15, lk4);

  // rgb = hv @ Wr + br  (padded-weight MFMA, cols l15<3 real)
  {
    f4 accr[2];
    accr[0] = (f4){0.f, 0.f, 0.f, 0.f};
    accr[1] = (f4){0.f, 0.f, 0.f, 0.f};
    phase1<4>(accr, h, 256, ws + OFF_WR, 128, l15, lk8);
    if (l15 < 3) {
      const float bb = A.br[l15];
#pragma unroll
      for (int rt = 0; rt < 2; ++rt)
#pragma unroll
        for (int j = 0; j < 4; ++j)
          A.out[(size_t)(rowg0 + rt * 16 + lk4 + j) * 4 + l15] = accr[rt][j] + bb;
    }
  }
}

// ---------------------------------------------------------------------------
extern "C" void kernel_launch(void* const* d_in, const int* in_sizes, int n_in,
                              void* d_out, int out_size, void* d_ws, size_t ws_size,
                              hipStream_t stream) {
  // d_in order: x, W0,b0, W1,b1, ..., W7,b7, Wf,bf, Wa,ba, Wv,bv, Wr,br
  RepackArgs ra;
  ra.W0 = (const float*)d_in[1];  ra.W1 = (const float*)d_in[3];
  ra.W2 = (const float*)d_in[5];  ra.W3 = (const float*)d_in[7];
  ra.W4 = (const float*)d_in[9];  ra.W5 = (const float*)d_in[11];
  ra.W6 = (const float*)d_in[13]; ra.W7 = (const float*)d_in[15];
  ra.Wf = (const float*)d_in[17]; ra.Wv = (const float*)d_in[21];
  ra.Wa = (const float*)d_in[19]; ra.Wr = (const float*)d_in[23];
  ra.ws = (unsigned short*)d_ws;
  repack_kernel<<<(WS_TOTAL + 255) / 256, 256, 0, stream>>>(ra);

  MainArgs ma;
  ma.x   = (const float*)d_in[0];
  ma.ws  = (const unsigned short*)d_ws;
  ma.b0  = (const float*)d_in[2];  ma.b1 = (const float*)d_in[4];
  ma.b2  = (const float*)d_in[6];  ma.b3 = (const float*)d_in[8];
  ma.b4  = (const float*)d_in[10]; ma.b5 = (const float*)d_in[12];
  ma.b6  = (const float*)d_in[14]; ma.b7 = (const float*)d_in[16];
  ma.bfc = (const float*)d_in[18];
  ma.ba  = (const float*)d_in[20];
  ma.bv  = (const float*)d_in[22];
  ma.br  = (const float*)d_in[24];
  ma.out = (float*)d_out;

  const int n    = in_sizes[0] / 126;   // 131072
  const int grid = n / 128;             // 1024 blocks (4 waves x 32 rows)

  hipFuncSetAttribute(reinterpret_cast<const void*>(nerf_kernel),
                      hipFuncAttributeMaxDynamicSharedMemorySize, 81920);
  nerf_kernel<<<grid, 256, 81920, stream>>>(ma);
}